// Round 17
// baseline (1099.229 us; speedup 1.0000x reference)
//
#include <hip/hip_runtime.h>
#include <hip/hip_bf16.h>
#include <hip/hip_fp16.h>
#include <cstdint>

// ---------------------------------------------------------------------------
// RWKV6 attention: f16-MFMA GEMMs + lean chunked scan + a_gen + MFMA correction.
//   Round 17: scan back to r15 shape (8k x 4v, S[32]) with a VGPR diet to get
//   under the 64-VGPR wave cap: unioned staging reg (E/V/RU in one uint4) and
//   ring depth 3. Target: 1024 blocks fully resident (16 waves/CU).
// ---------------------------------------------------------------------------

typedef _Float16 half8 __attribute__((ext_vector_type(8)));
typedef float f32x4 __attribute__((ext_vector_type(4)));

#define CL 256          // chunk length (T/8)
#define NP (CL / 2)     // pair-steps per chunk
#define NC 8            // chunks

__device__ __forceinline__ float hbits2f(unsigned short us) {
    __half h; *reinterpret_cast<unsigned short*>(&h) = us; return __half2float(h);
}
__device__ __forceinline__ unsigned short f2h(float f) {
    __half h = __float2half(f);
    return *reinterpret_cast<unsigned short*>(&h);
}
__device__ __forceinline__ float2 up2(unsigned int u) {
    return make_float2(hbits2f((unsigned short)(u & 0xFFFF)),
                       hbits2f((unsigned short)(u >> 16)));
}
__device__ __forceinline__ void gload_lds16(const void* g, void* l) {
    __builtin_amdgcn_global_load_lds(
        (const __attribute__((address_space(1))) unsigned*)g,
        (__attribute__((address_space(3))) unsigned*)l, 16, 0, 0);
}

// ---------------- fused weight cast (all 9 tensors, one dispatch) -----------
__global__ __launch_bounds__(256) void cast_all(
    const float* __restrict__ p0, const float* __restrict__ p1,
    const float* __restrict__ p2, const float* __restrict__ p3,
    const float* __restrict__ p4, const float* __restrict__ p5,
    const float* __restrict__ p6, const float* __restrict__ p7,
    const float* __restrict__ p8, __half* __restrict__ dst)
{
    const int v = blockIdx.x * 256 + threadIdx.x;   // 0..1155071
    const float* s; int off;
    if      (v < 40960)  { s = p0; off = v; }
    else if (v < 81920)  { s = p1; off = v - 40960; }
    else if (v < 212992) { s = p2; off = v - 81920; }
    else if (v < 344064) { s = p3; off = v - 212992; }
    else if (v < 606208) { s = p4; off = v - 344064; }
    else if (v < 868352) { s = p5; off = v - 606208; }
    else if (v < 884736) { s = p6; off = v - 868352; }
    else if (v < 892928) { s = p7; off = v - 884736; }
    else                 { s = p8; off = v - 892928; }
    const float4 f = *(const float4*)(s + (size_t)off * 4);
    ushort4 u;
    u.x = f2h(f.x); u.y = f2h(f.y); u.z = f2h(f.z); u.w = f2h(f.w);
    *(ushort4*)(dst + (size_t)v * 4) = u;
}

// ---------------- x -> f16 cast (into dead xwh slot) ------------------------
__global__ __launch_bounds__(256) void cast_x(const float* __restrict__ x,
                                              __half* __restrict__ xh)
{
    const size_t v = (size_t)blockIdx.x * 256 + threadIdx.x;  // M*1024/4 vec4
    const float4 f = *(const float4*)(x + v * 4);
    ushort4 u;
    u.x = f2h(f.x); u.y = f2h(f.y); u.z = f2h(f.z); u.w = f2h(f.w);
    *(ushort4*)(xh + v * 4) = u;
}

// ---------------- token shift (f16 out) -------------------------------------
__global__ void k_xw_h(const float* __restrict__ X, const float* __restrict__ mu,
                       __half* __restrict__ XW, int M, int T)
{
    const size_t i4 = (size_t)blockIdx.x * blockDim.x + threadIdx.x;
    if (i4 >= (size_t)M * 256) return;
    const size_t idx = i4 * 4;
    const int m = (int)(idx >> 10);
    const int d = (int)(idx & 1023);
    const int t = m & (T - 1);
    const float4 xv = *(const float4*)(X + idx);
    const float4 m4 = *(const float4*)(mu + d);
    float4 xp = make_float4(0.f, 0.f, 0.f, 0.f);
    if (t > 0) xp = *(const float4*)(X + idx - 1024);
    ushort4 o;
    o.x = f2h(xv.x + (xp.x - xv.x) * m4.x);
    o.y = f2h(xv.y + (xp.y - xv.y) * m4.y);
    o.z = f2h(xv.z + (xp.z - xv.z) * m4.z);
    o.w = f2h(xv.w + (xp.w - xv.w) * m4.w);
    *(ushort4*)(XW + idx) = o;
}

// ---------------- f16 MFMA GEMM: C[M,N] = A[M,K] @ B[N,K]^T -----------------
// epi: 0 f16 plain, 1 f16 tanh, 2 f16 bias+delta-lerp(Xh f16, shift-dedup),
//      3 f16 bias, 4 f32 plain
__global__ __launch_bounds__(256) void gemm16(
    const __half* __restrict__ A, int lda,
    const __half* __restrict__ B, int ldb,
    void* __restrict__ Cv, int ldc,
    int M, int N, int K,
    const float* __restrict__ bias, int epi,
    const __half* __restrict__ X, int T)
{
    __shared__ __align__(16) _Float16 As[128 * 32];
    __shared__ __align__(16) _Float16 Bs[128 * 32];

    const int tid = threadIdx.x;

    const int nwg = gridDim.x * gridDim.y;
    int p = blockIdx.y * gridDim.x + blockIdx.x;
    if (!(nwg & 7)) p = (p & 7) * (nwg >> 3) + (p >> 3);
    const int bx = p % gridDim.x, by = p / gridDim.x;

    const int m0 = by * 128;
    const int n0 = bx * 128;
    const int wave = tid >> 6, lane = tid & 63;
    const int wm = wave >> 1, wn = wave & 1;
    const int lr = lane & 15, lk = lane >> 4;

    const int srow = tid >> 2;          // 0..63
    const int scol = (tid & 3) * 8;     // halfs
    const int arow0 = m0 + srow, arow1 = m0 + 64 + srow;
    int brow0 = n0 + srow;      if (brow0 >= N) brow0 = N - 1;
    int brow1 = n0 + 64 + srow; if (brow1 >= N) brow1 = N - 1;
    char* dA = (char*)As + tid * 16;
    char* dB = (char*)Bs + tid * 16;

    f32x4 acc[4][4] = {};

    for (int k0 = 0; k0 < K; k0 += 32) {
        const __half* gA0 = A + (size_t)arow0 * lda + k0 + scol;
        const __half* gA1 = A + (size_t)arow1 * lda + k0 + scol;
        const __half* gB0 = B + (size_t)brow0 * ldb + k0 + scol;
        const __half* gB1 = B + (size_t)brow1 * ldb + k0 + scol;
        __syncthreads();
        gload_lds16(gA0, dA);
        gload_lds16(gA1, dA + 4096);
        gload_lds16(gB0, dB);
        gload_lds16(gB1, dB + 4096);
        __syncthreads();

        half8 af[4], bf[4];
#pragma unroll
        for (int f = 0; f < 4; f++) {
            af[f] = *(const half8*)&As[(wm * 64 + f * 16 + lr) * 32 + lk * 8];
            bf[f] = *(const half8*)&Bs[(wn * 64 + f * 16 + lr) * 32 + lk * 8];
        }
#pragma unroll
        for (int fm = 0; fm < 4; fm++)
#pragma unroll
            for (int fn = 0; fn < 4; fn++)
                acc[fm][fn] = __builtin_amdgcn_mfma_f32_16x16x32_f16(
                    af[fm], bf[fn], acc[fm][fn], 0, 0, 0);
    }

#pragma unroll
    for (int fm = 0; fm < 4; fm++) {
#pragma unroll
        for (int fn = 0; fn < 4; fn++) {
            const int gm0 = m0 + wm * 64 + fm * 16 + lk * 4;
            const int gn = n0 + wn * 64 + fn * 16 + lr;
            if (gn >= N) continue;
            float xprev = 0.f;
            if (epi == 2 && (gm0 & (T - 1)))
                xprev = __half2float(X[(size_t)(gm0 - 1) * 1024 + gn]);
#pragma unroll
            for (int j = 0; j < 4; j++) {
                const int gm = gm0 + j;
                float a = acc[fm][fn][j];
                if (epi == 1) {
                    a = tanhf(a);
                    ((__half*)Cv)[(size_t)gm * ldc + gn] = __float2half(a);
                } else if (epi == 2) {
                    a += bias[gn];
                    const float xv = __half2float(X[(size_t)gm * 1024 + gn]);
                    ((__half*)Cv)[(size_t)gm * ldc + gn] =
                        __float2half(xv + (xprev - xv) * a);
                    xprev = xv;
                } else if (epi == 3) {
                    a += bias[gn];
                    ((__half*)Cv)[(size_t)gm * ldc + gn] = __float2half(a);
                } else if (epi == 4) {
                    ((float*)Cv)[(size_t)gm * ldc + gn] = a;
                } else {
                    ((__half*)Cv)[(size_t)gm * ldc + gn] = __float2half(a);
                }
            }
        }
    }
}

// ---------------- prepass: pack E-line + ru ---------------------------------
__global__ __launch_bounds__(256) void k_prep(
    const __half* __restrict__ R, const __half* __restrict__ Kk,
    const __half* __restrict__ W, const float* __restrict__ bonus,
    unsigned* __restrict__ Eu, float* __restrict__ RU, int T)
{
    const int tok = blockIdx.x;
    const int b = tok >> 11, t = tok & 2047;
    const int h = threadIdx.x >> 6, lane = threadIdx.x & 63;
    const size_t base = (size_t)tok * 512 + h * 128 + 2 * lane;
    const unsigned rr = *(const unsigned*)(R + base);
    const unsigned kk = *(const unsigned*)(Kk + base);
    const unsigned ww = *(const unsigned*)(W + base);
    const float2 rf = up2(rr), kf = up2(kk), wf = up2(ww);
    const float d0 = __expf(-__expf(wf.x));
    const float d1 = __expf(-__expf(wf.y));
    const float2 uf = *(const float2*)(bonus + h * 128 + 2 * lane);
    float ru = rf.x * uf.x * kf.x + rf.y * uf.y * kf.y;
#pragma unroll
    for (int off = 1; off < 64; off <<= 1) ru += __shfl_xor(ru, off);
    const int bh = b * 4 + h;
    unsigned* ep = Eu + (size_t)(bh * T + t) * 192;
    uint2 rkw;
    rkw.x = (rr & 0xFFFFu) | (kk << 16);
    rkw.y = (rr >> 16) | (kk & 0xFFFF0000u);
    *(uint2*)(ep + 2 * lane) = rkw;
    ep[128 + lane] = (unsigned)f2h(d0) | ((unsigned)f2h(d1) << 16);
    if (lane == 0) RU[(size_t)bh * T + t] = ru;
}

// ---------------- a_gen: a_t = r_t ⊙ D(t0..t-1), Abuf = full-chunk product --
__global__ __launch_bounds__(128) void a_gen(
    const unsigned* __restrict__ Eu, __half* __restrict__ Ab,
    float* __restrict__ Abuf, int T)
{
    const int p = blockIdx.x;
    const int l = (p & 7) * 28 + (p >> 3);   // 224 blocks, bijective
    const int bh = l / 7, ci = l - bh * 7;
    const int c = ci + 1;
    const int k = threadIdx.x;
    const int t0 = c * CL;
    const unsigned* ep = Eu + (size_t)(bh * T + t0) * 192;
    __half* ap = Ab + ((size_t)bh * T + t0) * 128 + k;
    const int sel = (k & 1) * 16;
    float D = 1.f;
#pragma unroll 4
    for (int t = 0; t < CL; ++t) {
        const unsigned* e = ep + (size_t)t * 192;
        const unsigned rk = e[k];
        const unsigned dw = e[128 + (k >> 1)];
        const float r = hbits2f((unsigned short)(rk & 0xFFFF));
        const float d = hbits2f((unsigned short)((dw >> sel) & 0xFFFF));
        ap[(size_t)t * 128] = __float2half(r * D);
        D *= d;
    }
    if (c < NC - 1) Abuf[(size_t)(c * 32 + bh) * 128 + k] = D;
}

// ---------------- lean chunked scan (paired steps, 8k x 4v, ring-3) ---------
// Block = (bh, c, vq of 64 v-cols): 256 thr; kg = tid&15 (8 k), vg = tid>>4
// (4 v). S[32]. Waves 0,1 stage steps 2p,2p+1 via ONE unioned uint4 register
// (E lanes<48, V lanes 48-55, RU lane 56 in .x). 3-slot LDS ring; raw
// s_barrier + lgkmcnt(0) per pair. rk XOR-swizzled.
__global__ __launch_bounds__(256) void rwkv_scan(
    const uint4* __restrict__ E, const __half* __restrict__ V,
    const float* __restrict__ RU, __half* __restrict__ Cout,
    __half* __restrict__ O, int T)
{
    __shared__ uint4 sE[3][96];
    __shared__ uint4 sV[3][16];
    __shared__ float sRU[3][2];

    const int p = blockIdx.x;
    const int l = (p & 7) * 128 + (p >> 3);       // 1024 blocks, bijective
    const int bh = l >> 5, c = (l >> 2) & 7, vq = l & 3;
    const int b = bh >> 2, h = bh & 3;
    const int tid = threadIdx.x;
    const int w = tid >> 6, lane = tid & 63;
    const int kg = tid & 15, vg = tid >> 4;
    const int t0 = c * CL;

    const uint4* Eg = E + (size_t)(bh * T + t0) * 48;
    const uint4* Vgp = (const uint4*)(V + ((size_t)b * T + t0) * 1024 + h * 256 + vq * 64);
    const unsigned* RUp = (const unsigned*)(RU + (size_t)bh * T + t0);
    __half* Op = O + ((size_t)b * T + t0) * 1024 + h * 256 + vq * 64 + vg * 4;

    float S[32];
#pragma unroll
    for (int j = 0; j < 32; j++) S[j] = 0.f;

    const int i0 = (kg * 2) ^ ((kg * 2) >> 3);
    const int i1 = (kg * 2 + 1) ^ ((kg * 2 + 1) >> 3);

#define ISSUE(BE, PP)                                                         \
    if (w < 2 && (PP) < NP) {                                                 \
        const int tt = (PP) * 2 + w;                                          \
        if (lane < 48)      BE = Eg[(size_t)tt * 48 + lane];                  \
        else if (lane < 56) BE = Vgp[(size_t)tt * 128 + (lane - 48)];         \
        else if (lane == 56) BE.x = RUp[tt];                                  \
    }

#define STAGE(BE, SLOT)                                                       \
    if (w < 2) {                                                              \
        if (lane < 32)      sE[SLOT][w * 48 + (lane ^ (lane >> 3))] = BE;     \
        else if (lane < 48) sE[SLOT][w * 48 + lane] = BE;                     \
        else if (lane < 56) sV[SLOT][w * 8 + (lane - 48)] = BE;               \
        else if (lane == 56) sRU[SLOT][w] = __uint_as_float(BE.x);            \
    }

#define BAR() do {                                                            \
        asm volatile("s_waitcnt lgkmcnt(0)" ::: "memory");                    \
        __builtin_amdgcn_s_barrier();                                         \
        __builtin_amdgcn_sched_barrier(0);                                    \
    } while (0)

#define COMPUTE(SLOT, SUB, TT)                                                \
    {                                                                         \
        const uint4 rka = sE[SLOT][(SUB) * 48 + i0];                          \
        const uint4 rkb = sE[SLOT][(SUB) * 48 + i1];                          \
        const uint4 dq  = sE[SLOT][(SUB) * 48 + 32 + kg];                     \
        const uint2 vw  = *(const uint2*)((const unsigned*)&sV[SLOT][(SUB) * 8] + vg * 2); \
        const unsigned rw_[8] = {rka.x, rka.y, rka.z, rka.w,                  \
                                 rkb.x, rkb.y, rkb.z, rkb.w};                 \
        const unsigned dw_[4] = {dq.x, dq.y, dq.z, dq.w};                     \
        float r_[8], k_[8], d_[8], vv_[4];                                    \
        _Pragma("unroll") for (int j = 0; j < 8; j++) {                       \
            const float2 rk = up2(rw_[j]); r_[j] = rk.x; k_[j] = rk.y;        \
        }                                                                     \
        _Pragma("unroll") for (int j = 0; j < 4; j++) {                       \
            const float2 dd = up2(dw_[j]); d_[2 * j] = dd.x; d_[2 * j + 1] = dd.y; \
        }                                                                     \
        { const float2 va = up2(vw.x), vb = up2(vw.y);                        \
          vv_[0] = va.x; vv_[1] = va.y; vv_[2] = vb.x; vv_[3] = vb.y; }       \
        float osum[4] = {0.f, 0.f, 0.f, 0.f};                                 \
        _Pragma("unroll") for (int kk = 0; kk < 8; kk++) {                    \
            _Pragma("unroll") for (int vi = 0; vi < 4; vi++) {                \
                osum[vi] = fmaf(r_[kk], S[kk * 4 + vi], osum[vi]);            \
                S[kk * 4 + vi] = fmaf(d_[kk], S[kk * 4 + vi], k_[kk] * vv_[vi]); \
            }                                                                 \
        }                                                                     \
        _Pragma("unroll") for (int vi = 0; vi < 4; vi++) {                    \
            osum[vi] += __shfl_xor(osum[vi], 1);                              \
            osum[vi] += __shfl_xor(osum[vi], 2);                              \
            osum[vi] += __shfl_xor(osum[vi], 4);                              \
            osum[vi] += __shfl_xor(osum[vi], 8);                              \
        }                                                                     \
        if (kg == 0) {                                                        \
            const float ru_ = sRU[SLOT][SUB];                                 \
            ushort4 ou;                                                       \
            ou.x = f2h(osum[0] + ru_ * vv_[0]);                               \
            ou.y = f2h(osum[1] + ru_ * vv_[1]);                               \
            ou.z = f2h(osum[2] + ru_ * vv_[2]);                               \
            ou.w = f2h(osum[3] + ru_ * vv_[3]);                               \
            *(ushort4*)(Op + (size_t)(TT) * 1024) = ou;                       \
        }                                                                     \
    }

#define COMPUTE2(SLOT, PP)  COMPUTE(SLOT, 0, (PP) * 2) COMPUTE(SLOT, 1, (PP) * 2 + 1)

    uint4 e0 = {}, e1 = {}, e2 = {};

    ISSUE(e0, 0)
    ISSUE(e1, 1)
    ISSUE(e2, 2)
    STAGE(e0, 0)
    BAR();

    for (int ps = 0; ps < 126; ps += 3) {
        STAGE(e1, 1)
        ISSUE(e0, ps + 3)
        COMPUTE2(0, ps)
        BAR();
        STAGE(e2, 2)
        ISSUE(e1, ps + 4)
        COMPUTE2(1, ps + 1)
        BAR();
        STAGE(e0, 0)
        ISSUE(e2, ps + 5)
        COMPUTE2(2, ps + 2)
        BAR();
    }
    // tail: pairs 126 (slot0, staged in last iter), 127 (in e1)
    STAGE(e1, 1)
    COMPUTE2(0, 126)
    BAR();
    COMPUTE2(1, 127)

    // chunk summaries (B_c transposed [v][k]) for c < NC-1
    if (c < NC - 1) {
        __half* Cw = Cout + ((size_t)c * 32 + bh) * 32768 +
                     (size_t)(vq * 64 + vg * 4) * 128 + kg * 8;
#pragma unroll
        for (int vi = 0; vi < 4; vi++) {
            unsigned su[4];
#pragma unroll
            for (int j = 0; j < 4; j++)
                su[j] = (unsigned)f2h(S[(2 * j) * 4 + vi]) |
                        ((unsigned)f2h(S[(2 * j + 1) * 4 + vi]) << 16);
            uint4 s4; s4.x = su[0]; s4.y = su[1]; s4.z = su[2]; s4.w = su[3];
            *(uint4*)(Cw + (size_t)vi * 128) = s4;
        }
    }
#undef ISSUE
#undef STAGE
#undef BAR
#undef COMPUTE
#undef COMPUTE2
}

// ---------------- combine: C[c-1] := S_start(c) (transposed [v][k]) ---------
__global__ __launch_bounds__(256) void rwkv_comb(
    __half* __restrict__ C, const float* __restrict__ A)
{
    const int gid = blockIdx.x * 256 + threadIdx.x;   // 1M threads
    const int bh = gid >> 15;
    const int elem = gid & 32767;
    const int k = elem & 127;
    float s = hbits2f(*(const unsigned short*)(C + (size_t)bh * 32768 + elem));
#pragma unroll
    for (int c = 1; c < NC - 1; ++c) {
        const float a = A[(size_t)(c * 32 + bh) * 128 + k];
        __half* cp = C + ((size_t)c * 32 + bh) * 32768 + elem;
        s = a * s + hbits2f(*(const unsigned short*)cp);
        *(unsigned short*)cp = f2h(s);
    }
}

// ---------------- correction: o += a @ S_start (128x128 MFMA tiles) ---------
__global__ __launch_bounds__(256) void corr_gemm(
    const __half* __restrict__ Abig, const __half* __restrict__ Cbuf,
    __half* __restrict__ O, int T)
{
    __shared__ __align__(16) _Float16 As[128 * 32];
    __shared__ __align__(16) _Float16 Bs[128 * 32];

    const int tid = threadIdx.x;
    const int p = blockIdx.x;
    const int l = (p & 7) * 112 + (p >> 3);    // 896 blocks, bijective
    const int bhc = l >> 2, mt = (l >> 1) & 1, nt = l & 1;
    const int bh = bhc / 7, ci = bhc - bh * 7;
    const int b = bh >> 2, h = bh & 3;
    const int t0 = (ci + 1) * CL + mt * 128;

    const __half* Ag = Abig + ((size_t)bh * T + t0) * 128;
    const __half* Bg = Cbuf + ((size_t)ci * 32 + bh) * 32768 + (size_t)nt * 128 * 128;
    __half* Og = O + ((size_t)b * T + t0) * 1024 + h * 256 + nt * 128;

    const int wave = tid >> 6, lane = tid & 63;
    const int wm = wave >> 1, wn = wave & 1;
    const int lr = lane & 15, lk = lane >> 4;
    const int srow = tid >> 2;
    const int scol = (tid & 3) * 8;
    char* dA = (char*)As + tid * 16;
    char* dB = (char*)Bs + tid * 16;

    f32x4 acc[4][4] = {};

    for (int k0 = 0; k0 < 128; k0 += 32) {
        const __half* gA0 = Ag + (size_t)srow * 128 + k0 + scol;
        const __half* gA1 = Ag + (size_t)(64 + srow) * 128 + k0 + scol;
        const __half* gB0 = Bg + (size_t)srow * 128 + k0 + scol;
        const __half* gB1 = Bg + (size_t)(64 + srow) * 128 + k0 + scol;
        __syncthreads();
        gload_lds16(gA0, dA);
        gload_lds16(gA1, dA + 4096);
        gload_lds16(gB0, dB);
        gload_lds16(gB1, dB + 4096);
        __syncthreads();

        half8 af[4], bf[4];
#pragma unroll
        for (int f = 0; f < 4; f++) {
            af[f] = *(const half8*)&As[(wm * 64 + f * 16 + lr) * 32 + lk * 8];
            bf[f] = *(const half8*)&Bs[(wn * 64 + f * 16 + lr) * 32 + lk * 8];
        }
#pragma unroll
        for (int fm = 0; fm < 4; fm++)
#pragma unroll
            for (int fn = 0; fn < 4; fn++)
                acc[fm][fn] = __builtin_amdgcn_mfma_f32_16x16x32_f16(
                    af[fm], bf[fn], acc[fm][fn], 0, 0, 0);
    }

#pragma unroll
    for (int fm = 0; fm < 4; fm++) {
#pragma unroll
        for (int fn = 0; fn < 4; fn++) {
#pragma unroll
            for (int j = 0; j < 4; j++) {
                const int row = wm * 64 + fm * 16 + lk * 4 + j;
                const int col = wn * 64 + fn * 16 + lr;
                __half* op = Og + (size_t)row * 1024 + col;
                *op = __float2half(__half2float(*op) + acc[fm][fn][j]);
            }
        }
    }
}

// ---------------- groupnorm + silu gate (f16 in/out) ------------------------
__global__ __launch_bounds__(256) void gn_gate(
    const __half* __restrict__ Obuf, const __half* __restrict__ G,
    const float* __restrict__ gnw, const float* __restrict__ gnb,
    __half* __restrict__ Y)
{
    const int token = blockIdx.x;
    const int wave = threadIdx.x >> 6, lane = threadIdx.x & 63;
    const size_t base = (size_t)token * 1024 + wave * 256 + lane * 4;
    const ushort4 xu = *(const ushort4*)(Obuf + base);
    const float x0 = hbits2f(xu.x), x1 = hbits2f(xu.y),
                x2 = hbits2f(xu.z), x3 = hbits2f(xu.w);
    float sum = x0 + x1 + x2 + x3;
    float ssq = x0 * x0 + x1 * x1 + x2 * x2 + x3 * x3;
#pragma unroll
    for (int off = 32; off >= 1; off >>= 1) {
        sum += __shfl_xor(sum, off);
        ssq += __shfl_xor(ssq, off);
    }
    const float mean = sum * (1.f / 256.f);
    const float var = ssq * (1.f / 256.f) - mean * mean;
    const float rstd = rsqrtf(var + 1e-5f);
    const int c0 = wave * 256 + lane * 4;
    const float4 w4 = *(const float4*)(gnw + c0);
    const float4 b4 = *(const float4*)(gnb + c0);
    const ushort4 gu = *(const ushort4*)(G + base);
    const float g0 = hbits2f(gu.x), g1 = hbits2f(gu.y),
                g2 = hbits2f(gu.z), g3 = hbits2f(gu.w);
    ushort4 y;
    y.x = f2h(((x0 - mean) * rstd * w4.x + b4.x) * (g0 / (1.f + __expf(-g0))));
    y.y = f2h(((x1 - mean) * rstd * w4.y + b4.y) * (g1 / (1.f + __expf(-g1))));
    y.z = f2h(((x2 - mean) * rstd * w4.z + b4.z) * (g2 / (1.f + __expf(-g2))));
    y.w = f2h(((x3 - mean) * rstd * w4.w + b4.w) * (g3 / (1.f + __expf(-g3))));
    *(ushort4*)(Y + base) = y;
}

// ---------------------------------------------------------------------------
extern "C" void kernel_launch(void* const* d_in, const int* in_sizes, int n_in,
                              void* d_out, int out_size, void* d_ws, size_t ws_size,
                              hipStream_t stream)
{
    (void)in_sizes; (void)n_in; (void)out_size; (void)ws_size;
    const float* x      = (const float*)d_in[0];
    const float* mu_x   = (const float*)d_in[1];
    const float* W_x1   = (const float*)d_in[2];
    const float* W_x2   = (const float*)d_in[3];
    const float* x_bias = (const float*)d_in[4];
    const float* W_r    = (const float*)d_in[5];
    const float* W_k    = (const float*)d_in[6];
    const float* W_v    = (const float*)d_in[7];
    const float* W_g    = (const float*)d_in[8];
    const float* A_w    = (const float*)d_in[9];
    const float* B_w    = (const float*)d_in[10];
    const float* b_w    = (const float*)d_in[11];
    const float* bonus  = (const float*)d_in[12];
    const float* gnw    = (const float*)d_in[13];
    const float* gnb    = (const float*)d_in[14];
    const float* W_o    = (const float*)d_in[15];

    const int B = 8, T = 2048, M = B * T;

    // d_out: [xw_h | inb_h] f16 -> xh (0-32MB, after z-GEMM) ->
    //        [E 48MiB | a 16MiB] -> final f32
    __half* xwh  = (__half*)d_out;
    __half* inbh = xwh + (size_t)M * 1024;
    __half* xh   = xwh;                               // reuses dead xwh slot
    __half* Abig = (__half*)((char*)d_out + (size_t)48 * 1024 * 1024);

    // ws layout (identical to round-8..16, proven to fit)
    __half* z   = (__half*)d_ws;                    // M*160
    __half* w1  = z   + (size_t)M * 160;            // M*64
    __half* rs  = w1  + (size_t)M * 64;             // M*512
    __half* ks  = rs  + (size_t)M * 512;            // M*512
    __half* wsm = ks  + (size_t)M * 512;            // M*512 (w stream)
    __half* vs  = wsm + (size_t)M * 512;            // M*1024
    __half* gs  = vs  + (size_t)M * 1024;           // M*1024
    float*  ru  = (float*)(gs + (size_t)M * 1024);  // 32*T f32
    __half* wgt = (__half*)(ru + (size_t)32 * T);   // f16 weights (contiguous)
    __half* oh  = rs;                               // overlay: o f16 (r+k dead)
    __half* yb  = wsm;                              // overlay: y f16 (post-corr)
    __half* Cbuf = wsm;                             // overlay: 7*32*32768 f16
    float*  Abuf = (float*)z;                       // overlay: 7*32*128 f32

    __half* W_x1h = wgt;                 // 160*1024
    __half* W_x2h = W_x1h + 163840;      // 1024*160
    __half* W_rh  = W_x2h + 163840;      // 512*1024
    __half* W_kh  = W_rh + 524288;
    __half* W_vh  = W_kh + 524288;       // 1024*1024
    __half* W_gh  = W_vh + 1048576;
    __half* A_wh  = W_gh + 1048576;      // 64*1024
    __half* B_wh  = A_wh + 65536;        // 512*64
    __half* W_oh  = B_wh + 32768;        // 1024*1024

    const dim3 blk(256);
    // one fused cast for all 9 weight tensors (dst = wgt, contiguous)
    cast_all<<<dim3(4512), blk, 0, stream>>>(W_x1, W_x2, W_r, W_k, W_v, W_g,
                                             A_w, B_w, W_o, wgt);

    // 1. xw = lerp(x, mu_x) -> f16
    k_xw_h<<<(M * 256 + 255) / 256, blk, 0, stream>>>(x, mu_x, xwh, M, T);

    auto ggrid = [&](int N) { return dim3((N + 127) / 128, M / 128); };

    // 2. z = tanh(xw @ W_x1^T)
    gemm16<<<ggrid(160), blk, 0, stream>>>(xwh, 1024, W_x1h, 1024, z, 160,
                                           M, 160, 1024, nullptr, 1, nullptr, T);

    // 2b. xh = f16(x) into dead xwh slot (feeds the 5 epi=2 epilogues)
    cast_x<<<dim3(16384), blk, 0, stream>>>(x, xh);

    // 3. branches
    for (int n = 0; n < 5; ++n) {
        gemm16<<<ggrid(1024), blk, 0, stream>>>(z + n * 32, 160, W_x2h + n * 32, 160,
                                                inbh, 1024, M, 1024, 32,
                                                x_bias + n * 1024, 2, xh, T);
        if (n == 1) {
            gemm16<<<ggrid(64), blk, 0, stream>>>(inbh, 1024, A_wh, 1024, w1, 64,
                                                  M, 64, 1024, nullptr, 1, nullptr, T);
            gemm16<<<ggrid(512), blk, 0, stream>>>(w1, 64, B_wh, 64, wsm, 512,
                                                   M, 512, 64, b_w, 3, nullptr, T);
        } else {
            __half* Cp = (n == 0) ? rs : (n == 2) ? ks : (n == 3) ? vs : gs;
            const __half* Wp = (n == 0) ? W_rh : (n == 2) ? W_kh : (n == 3) ? W_vh : W_gh;
            const int N = (n == 0 || n == 2) ? 512 : 1024;
            gemm16<<<ggrid(N), blk, 0, stream>>>(inbh, 1024, Wp, 1024, Cp, N,
                                                 M, N, 1024, nullptr, 0, nullptr, T);
        }
    }

    // 4. prepass -> packed E lines (d_out; xh/inbh dead), ru
    k_prep<<<dim3(M), blk, 0, stream>>>(rs, ks, wsm, bonus,
                                        (unsigned*)d_out, ru, T);

    // 4b. a_t = r⊙D prefix + Abuf (chunks 1..7)
    a_gen<<<dim3(224), dim3(128), 0, stream>>>((const unsigned*)d_out, Abig,
                                               Abuf, T);

    // 5a. lean scan (8k x 4v, ring-3): local outputs + chunk summaries
    rwkv_scan<<<dim3(1024), blk, 0, stream>>>(
        (const uint4*)d_out, vs, ru, Cbuf, oh, T);
    // 5b. combine -> Cbuf[c-1] = S_start(c)
    rwkv_comb<<<dim3(4096), blk, 0, stream>>>(Cbuf, Abuf);
    // 5c. correction: o += a @ S_start for chunks 1..7
    corr_gemm<<<dim3(896), blk, 0, stream>>>(Abig, Cbuf, oh, T);

    // 6. groupnorm + gate -> yb (Cbuf dead)
    gn_gate<<<dim3(M), blk, 0, stream>>>(oh, gs, gnw, gnb, yb);

    // 7. out = y @ W_o^T -> d_out f32 (E, a dead)
    gemm16<<<ggrid(1024), blk, 0, stream>>>(yb, 1024, W_oh, 1024, d_out, 1024,
                                            M, 1024, 1024, nullptr, 4, nullptr, T);
}

// Round 18
// 1060.188 us; speedup vs baseline: 1.0368x; 1.0368x over previous
//
#include <hip/hip_runtime.h>
#include <hip/hip_bf16.h>
#include <hip/hip_fp16.h>
#include <cstdint>

// ---------------------------------------------------------------------------
// RWKV6 attention: f16-MFMA GEMMs + lean chunked scan + a_gen + MFMA correction.
//   Round 18: scan reverted to r15 exact shape (8k x 4v, S[32], ring-4,
//   VGPR 76 — best measured 376us; r16/r17 probes both worse). cast_x fused
//   into k_xw_h (xh emitted to gs region; saves a 64MB x read + a dispatch).
// ---------------------------------------------------------------------------

typedef _Float16 half8 __attribute__((ext_vector_type(8)));
typedef float f32x4 __attribute__((ext_vector_type(4)));

#define CL 256          // chunk length (T/8)
#define NP (CL / 2)     // pair-steps per chunk
#define NC 8            // chunks

__device__ __forceinline__ float hbits2f(unsigned short us) {
    __half h; *reinterpret_cast<unsigned short*>(&h) = us; return __half2float(h);
}
__device__ __forceinline__ unsigned short f2h(float f) {
    __half h = __float2half(f);
    return *reinterpret_cast<unsigned short*>(&h);
}
__device__ __forceinline__ float2 up2(unsigned int u) {
    return make_float2(hbits2f((unsigned short)(u & 0xFFFF)),
                       hbits2f((unsigned short)(u >> 16)));
}
__device__ __forceinline__ void gload_lds16(const void* g, void* l) {
    __builtin_amdgcn_global_load_lds(
        (const __attribute__((address_space(1))) unsigned*)g,
        (__attribute__((address_space(3))) unsigned*)l, 16, 0, 0);
}

// ---------------- fused weight cast (all 9 tensors, one dispatch) -----------
__global__ __launch_bounds__(256) void cast_all(
    const float* __restrict__ p0, const float* __restrict__ p1,
    const float* __restrict__ p2, const float* __restrict__ p3,
    const float* __restrict__ p4, const float* __restrict__ p5,
    const float* __restrict__ p6, const float* __restrict__ p7,
    const float* __restrict__ p8, __half* __restrict__ dst)
{
    const int v = blockIdx.x * 256 + threadIdx.x;   // 0..1155071
    const float* s; int off;
    if      (v < 40960)  { s = p0; off = v; }
    else if (v < 81920)  { s = p1; off = v - 40960; }
    else if (v < 212992) { s = p2; off = v - 81920; }
    else if (v < 344064) { s = p3; off = v - 212992; }
    else if (v < 606208) { s = p4; off = v - 344064; }
    else if (v < 868352) { s = p5; off = v - 606208; }
    else if (v < 884736) { s = p6; off = v - 868352; }
    else if (v < 892928) { s = p7; off = v - 884736; }
    else                 { s = p8; off = v - 892928; }
    const float4 f = *(const float4*)(s + (size_t)off * 4);
    ushort4 u;
    u.x = f2h(f.x); u.y = f2h(f.y); u.z = f2h(f.z); u.w = f2h(f.w);
    *(ushort4*)(dst + (size_t)v * 4) = u;
}

// ---------------- token shift + x-cast (two f16 outputs) --------------------
__global__ void k_xw_h(const float* __restrict__ X, const float* __restrict__ mu,
                       __half* __restrict__ XW, __half* __restrict__ XH,
                       int M, int T)
{
    const size_t i4 = (size_t)blockIdx.x * blockDim.x + threadIdx.x;
    if (i4 >= (size_t)M * 256) return;
    const size_t idx = i4 * 4;
    const int m = (int)(idx >> 10);
    const int d = (int)(idx & 1023);
    const int t = m & (T - 1);
    const float4 xv = *(const float4*)(X + idx);
    const float4 m4 = *(const float4*)(mu + d);
    float4 xp = make_float4(0.f, 0.f, 0.f, 0.f);
    if (t > 0) xp = *(const float4*)(X + idx - 1024);
    ushort4 o;
    o.x = f2h(xv.x + (xp.x - xv.x) * m4.x);
    o.y = f2h(xv.y + (xp.y - xv.y) * m4.y);
    o.z = f2h(xv.z + (xp.z - xv.z) * m4.z);
    o.w = f2h(xv.w + (xp.w - xv.w) * m4.w);
    *(ushort4*)(XW + idx) = o;
    ushort4 u;
    u.x = f2h(xv.x); u.y = f2h(xv.y); u.z = f2h(xv.z); u.w = f2h(xv.w);
    *(ushort4*)(XH + idx) = u;
}

// ---------------- f16 MFMA GEMM: C[M,N] = A[M,K] @ B[N,K]^T -----------------
// epi: 0 f16 plain, 1 f16 tanh, 2 f16 bias+delta-lerp(Xh f16, shift-dedup),
//      3 f16 bias, 4 f32 plain
__global__ __launch_bounds__(256) void gemm16(
    const __half* __restrict__ A, int lda,
    const __half* __restrict__ B, int ldb,
    void* __restrict__ Cv, int ldc,
    int M, int N, int K,
    const float* __restrict__ bias, int epi,
    const __half* __restrict__ X, int T)
{
    __shared__ __align__(16) _Float16 As[128 * 32];
    __shared__ __align__(16) _Float16 Bs[128 * 32];

    const int tid = threadIdx.x;

    const int nwg = gridDim.x * gridDim.y;
    int p = blockIdx.y * gridDim.x + blockIdx.x;
    if (!(nwg & 7)) p = (p & 7) * (nwg >> 3) + (p >> 3);
    const int bx = p % gridDim.x, by = p / gridDim.x;

    const int m0 = by * 128;
    const int n0 = bx * 128;
    const int wave = tid >> 6, lane = tid & 63;
    const int wm = wave >> 1, wn = wave & 1;
    const int lr = lane & 15, lk = lane >> 4;

    const int srow = tid >> 2;          // 0..63
    const int scol = (tid & 3) * 8;     // halfs
    const int arow0 = m0 + srow, arow1 = m0 + 64 + srow;
    int brow0 = n0 + srow;      if (brow0 >= N) brow0 = N - 1;
    int brow1 = n0 + 64 + srow; if (brow1 >= N) brow1 = N - 1;
    char* dA = (char*)As + tid * 16;
    char* dB = (char*)Bs + tid * 16;

    f32x4 acc[4][4] = {};

    for (int k0 = 0; k0 < K; k0 += 32) {
        const __half* gA0 = A + (size_t)arow0 * lda + k0 + scol;
        const __half* gA1 = A + (size_t)arow1 * lda + k0 + scol;
        const __half* gB0 = B + (size_t)brow0 * ldb + k0 + scol;
        const __half* gB1 = B + (size_t)brow1 * ldb + k0 + scol;
        __syncthreads();
        gload_lds16(gA0, dA);
        gload_lds16(gA1, dA + 4096);
        gload_lds16(gB0, dB);
        gload_lds16(gB1, dB + 4096);
        __syncthreads();

        half8 af[4], bf[4];
#pragma unroll
        for (int f = 0; f < 4; f++) {
            af[f] = *(const half8*)&As[(wm * 64 + f * 16 + lr) * 32 + lk * 8];
            bf[f] = *(const half8*)&Bs[(wn * 64 + f * 16 + lr) * 32 + lk * 8];
        }
#pragma unroll
        for (int fm = 0; fm < 4; fm++)
#pragma unroll
            for (int fn = 0; fn < 4; fn++)
                acc[fm][fn] = __builtin_amdgcn_mfma_f32_16x16x32_f16(
                    af[fm], bf[fn], acc[fm][fn], 0, 0, 0);
    }

#pragma unroll
    for (int fm = 0; fm < 4; fm++) {
#pragma unroll
        for (int fn = 0; fn < 4; fn++) {
            const int gm0 = m0 + wm * 64 + fm * 16 + lk * 4;
            const int gn = n0 + wn * 64 + fn * 16 + lr;
            if (gn >= N) continue;
            float xprev = 0.f;
            if (epi == 2 && (gm0 & (T - 1)))
                xprev = __half2float(X[(size_t)(gm0 - 1) * 1024 + gn]);
#pragma unroll
            for (int j = 0; j < 4; j++) {
                const int gm = gm0 + j;
                float a = acc[fm][fn][j];
                if (epi == 1) {
                    a = tanhf(a);
                    ((__half*)Cv)[(size_t)gm * ldc + gn] = __float2half(a);
                } else if (epi == 2) {
                    a += bias[gn];
                    const float xv = __half2float(X[(size_t)gm * 1024 + gn]);
                    ((__half*)Cv)[(size_t)gm * ldc + gn] =
                        __float2half(xv + (xprev - xv) * a);
                    xprev = xv;
                } else if (epi == 3) {
                    a += bias[gn];
                    ((__half*)Cv)[(size_t)gm * ldc + gn] = __float2half(a);
                } else if (epi == 4) {
                    ((float*)Cv)[(size_t)gm * ldc + gn] = a;
                } else {
                    ((__half*)Cv)[(size_t)gm * ldc + gn] = __float2half(a);
                }
            }
        }
    }
}

// ---------------- prepass: pack E-line + ru ---------------------------------
__global__ __launch_bounds__(256) void k_prep(
    const __half* __restrict__ R, const __half* __restrict__ Kk,
    const __half* __restrict__ W, const float* __restrict__ bonus,
    unsigned* __restrict__ Eu, float* __restrict__ RU, int T)
{
    const int tok = blockIdx.x;
    const int b = tok >> 11, t = tok & 2047;
    const int h = threadIdx.x >> 6, lane = threadIdx.x & 63;
    const size_t base = (size_t)tok * 512 + h * 128 + 2 * lane;
    const unsigned rr = *(const unsigned*)(R + base);
    const unsigned kk = *(const unsigned*)(Kk + base);
    const unsigned ww = *(const unsigned*)(W + base);
    const float2 rf = up2(rr), kf = up2(kk), wf = up2(ww);
    const float d0 = __expf(-__expf(wf.x));
    const float d1 = __expf(-__expf(wf.y));
    const float2 uf = *(const float2*)(bonus + h * 128 + 2 * lane);
    float ru = rf.x * uf.x * kf.x + rf.y * uf.y * kf.y;
#pragma unroll
    for (int off = 1; off < 64; off <<= 1) ru += __shfl_xor(ru, off);
    const int bh = b * 4 + h;
    unsigned* ep = Eu + (size_t)(bh * T + t) * 192;
    uint2 rkw;
    rkw.x = (rr & 0xFFFFu) | (kk << 16);
    rkw.y = (rr >> 16) | (kk & 0xFFFF0000u);
    *(uint2*)(ep + 2 * lane) = rkw;
    ep[128 + lane] = (unsigned)f2h(d0) | ((unsigned)f2h(d1) << 16);
    if (lane == 0) RU[(size_t)bh * T + t] = ru;
}

// ---------------- a_gen: a_t = r_t ⊙ D(t0..t-1), Abuf = full-chunk product --
__global__ __launch_bounds__(128) void a_gen(
    const unsigned* __restrict__ Eu, __half* __restrict__ Ab,
    float* __restrict__ Abuf, int T)
{
    const int p = blockIdx.x;
    const int l = (p & 7) * 28 + (p >> 3);   // 224 blocks, bijective
    const int bh = l / 7, ci = l - bh * 7;
    const int c = ci + 1;
    const int k = threadIdx.x;
    const int t0 = c * CL;
    const unsigned* ep = Eu + (size_t)(bh * T + t0) * 192;
    __half* ap = Ab + ((size_t)bh * T + t0) * 128 + k;
    const int sel = (k & 1) * 16;
    float D = 1.f;
#pragma unroll 4
    for (int t = 0; t < CL; ++t) {
        const unsigned* e = ep + (size_t)t * 192;
        const unsigned rk = e[k];
        const unsigned dw = e[128 + (k >> 1)];
        const float r = hbits2f((unsigned short)(rk & 0xFFFF));
        const float d = hbits2f((unsigned short)((dw >> sel) & 0xFFFF));
        ap[(size_t)t * 128] = __float2half(r * D);
        D *= d;
    }
    if (c < NC - 1) Abuf[(size_t)(c * 32 + bh) * 128 + k] = D;
}

// ---------------- lean chunked scan (paired steps, 8k x 4v, ring-4) ---------
// r15-exact configuration (best measured: 376us, VGPR 76, occ ~26%).
__global__ __launch_bounds__(256) void rwkv_scan(
    const uint4* __restrict__ E, const __half* __restrict__ V,
    const float* __restrict__ RU, __half* __restrict__ Cout,
    __half* __restrict__ O, int T)
{
    __shared__ uint4 sE[4][96];
    __shared__ uint4 sV[4][16];
    __shared__ float sRU[4][2];

    const int p = blockIdx.x;
    const int l = (p & 7) * 128 + (p >> 3);       // 1024 blocks, bijective
    const int bh = l >> 5, c = (l >> 2) & 7, vq = l & 3;
    const int b = bh >> 2, h = bh & 3;
    const int tid = threadIdx.x;
    const int w = tid >> 6, lane = tid & 63;
    const int kg = tid & 15, vg = tid >> 4;
    const int t0 = c * CL;

    const uint4* Eg = E + (size_t)(bh * T + t0) * 48;
    const uint4* Vgp = (const uint4*)(V + ((size_t)b * T + t0) * 1024 + h * 256 + vq * 64);
    const float* RUp = RU + (size_t)bh * T + t0;
    __half* Op = O + ((size_t)b * T + t0) * 1024 + h * 256 + vq * 64 + vg * 4;

    float S[32];
#pragma unroll
    for (int j = 0; j < 32; j++) S[j] = 0.f;

    const int i0 = (kg * 2) ^ ((kg * 2) >> 3);
    const int i1 = (kg * 2 + 1) ^ ((kg * 2 + 1) >> 3);

#define ISSUE(BE, BV, BR, PP)                                                 \
    if (w < 2 && (PP) < NP) {                                                 \
        const int tt = (PP) * 2 + w;                                          \
        if (lane < 48)      BE = Eg[(size_t)tt * 48 + lane];                  \
        else if (lane < 56) BV = Vgp[(size_t)tt * 128 + (lane - 48)];         \
        if (lane == 56)     BR = RUp[tt];                                     \
    }

#define STAGE(BE, BV, BR, SLOT)                                               \
    if (w < 2) {                                                              \
        if (lane < 32)      sE[SLOT][w * 48 + (lane ^ (lane >> 3))] = BE;     \
        else if (lane < 48) sE[SLOT][w * 48 + lane] = BE;                     \
        else if (lane < 56) sV[SLOT][w * 8 + (lane - 48)] = BV;               \
        if (lane == 56)     sRU[SLOT][w] = BR;                                \
    }

#define BAR() do {                                                            \
        asm volatile("s_waitcnt lgkmcnt(0)" ::: "memory");                    \
        __builtin_amdgcn_s_barrier();                                         \
        __builtin_amdgcn_sched_barrier(0);                                    \
    } while (0)

#define COMPUTE(SLOT, SUB, TT)                                                \
    {                                                                         \
        const uint4 rka = sE[SLOT][(SUB) * 48 + i0];                          \
        const uint4 rkb = sE[SLOT][(SUB) * 48 + i1];                          \
        const uint4 dq  = sE[SLOT][(SUB) * 48 + 32 + kg];                     \
        const uint2 vw  = *(const uint2*)((const unsigned*)&sV[SLOT][(SUB) * 8] + vg * 2); \
        const unsigned rw_[8] = {rka.x, rka.y, rka.z, rka.w,                  \
                                 rkb.x, rkb.y, rkb.z, rkb.w};                 \
        const unsigned dw_[4] = {dq.x, dq.y, dq.z, dq.w};                     \
        float r_[8], k_[8], d_[8], vv_[4];                                    \
        _Pragma("unroll") for (int j = 0; j < 8; j++) {                       \
            const float2 rk = up2(rw_[j]); r_[j] = rk.x; k_[j] = rk.y;        \
        }                                                                     \
        _Pragma("unroll") for (int j = 0; j < 4; j++) {                       \
            const float2 dd = up2(dw_[j]); d_[2 * j] = dd.x; d_[2 * j + 1] = dd.y; \
        }                                                                     \
        { const float2 va = up2(vw.x), vb = up2(vw.y);                        \
          vv_[0] = va.x; vv_[1] = va.y; vv_[2] = vb.x; vv_[3] = vb.y; }       \
        float osum[4] = {0.f, 0.f, 0.f, 0.f};                                 \
        _Pragma("unroll") for (int kk = 0; kk < 8; kk++) {                    \
            _Pragma("unroll") for (int vi = 0; vi < 4; vi++) {                \
                osum[vi] = fmaf(r_[kk], S[kk * 4 + vi], osum[vi]);            \
                S[kk * 4 + vi] = fmaf(d_[kk], S[kk * 4 + vi], k_[kk] * vv_[vi]); \
            }                                                                 \
        }                                                                     \
        _Pragma("unroll") for (int vi = 0; vi < 4; vi++) {                    \
            osum[vi] += __shfl_xor(osum[vi], 1);                              \
            osum[vi] += __shfl_xor(osum[vi], 2);                              \
            osum[vi] += __shfl_xor(osum[vi], 4);                              \
            osum[vi] += __shfl_xor(osum[vi], 8);                              \
        }                                                                     \
        if (kg == 0) {                                                        \
            const float ru_ = sRU[SLOT][SUB];                                 \
            ushort4 ou;                                                       \
            ou.x = f2h(osum[0] + ru_ * vv_[0]);                               \
            ou.y = f2h(osum[1] + ru_ * vv_[1]);                               \
            ou.z = f2h(osum[2] + ru_ * vv_[2]);                               \
            ou.w = f2h(osum[3] + ru_ * vv_[3]);                               \
            *(ushort4*)(Op + (size_t)(TT) * 1024) = ou;                       \
        }                                                                     \
    }

#define COMPUTE2(SLOT, PP)  COMPUTE(SLOT, 0, (PP) * 2) COMPUTE(SLOT, 1, (PP) * 2 + 1)

    uint4 e0 = {}, e1 = {}, e2 = {}, e3 = {};
    uint4 v0 = {}, v1 = {}, v2 = {}, v3 = {};
    float r0 = 0.f, r1 = 0.f, r2 = 0.f, r3 = 0.f;

    ISSUE(e0, v0, r0, 0)
    ISSUE(e1, v1, r1, 1)
    ISSUE(e2, v2, r2, 2)
    ISSUE(e3, v3, r3, 3)
    STAGE(e0, v0, r0, 0)
    BAR();

    for (int ps = 0; ps < NP; ps += 4) {
        STAGE(e1, v1, r1, 1)
        ISSUE(e0, v0, r0, ps + 4)
        COMPUTE2(0, ps)
        BAR();
        STAGE(e2, v2, r2, 2)
        ISSUE(e1, v1, r1, ps + 5)
        COMPUTE2(1, ps + 1)
        BAR();
        STAGE(e3, v3, r3, 3)
        ISSUE(e2, v2, r2, ps + 6)
        COMPUTE2(2, ps + 2)
        BAR();
        if (ps + 4 < NP) STAGE(e0, v0, r0, 0)
        ISSUE(e3, v3, r3, ps + 7)
        COMPUTE2(3, ps + 3)
        BAR();
    }

    // chunk summaries (B_c transposed [v][k]) for c < NC-1
    if (c < NC - 1) {
        __half* Cw = Cout + ((size_t)c * 32 + bh) * 32768 +
                     (size_t)(vq * 64 + vg * 4) * 128 + kg * 8;
#pragma unroll
        for (int vi = 0; vi < 4; vi++) {
            unsigned su[4];
#pragma unroll
            for (int j = 0; j < 4; j++)
                su[j] = (unsigned)f2h(S[(2 * j) * 4 + vi]) |
                        ((unsigned)f2h(S[(2 * j + 1) * 4 + vi]) << 16);
            uint4 s4; s4.x = su[0]; s4.y = su[1]; s4.z = su[2]; s4.w = su[3];
            *(uint4*)(Cw + (size_t)vi * 128) = s4;
        }
    }
#undef ISSUE
#undef STAGE
#undef BAR
#undef COMPUTE
#undef COMPUTE2
}

// ---------------- combine: C[c-1] := S_start(c) (transposed [v][k]) ---------
__global__ __launch_bounds__(256) void rwkv_comb(
    __half* __restrict__ C, const float* __restrict__ A)
{
    const int gid = blockIdx.x * 256 + threadIdx.x;   // 1M threads
    const int bh = gid >> 15;
    const int elem = gid & 32767;
    const int k = elem & 127;
    float s = hbits2f(*(const unsigned short*)(C + (size_t)bh * 32768 + elem));
#pragma unroll
    for (int c = 1; c < NC - 1; ++c) {
        const float a = A[(size_t)(c * 32 + bh) * 128 + k];
        __half* cp = C + ((size_t)c * 32 + bh) * 32768 + elem;
        s = a * s + hbits2f(*(const unsigned short*)cp);
        *(unsigned short*)cp = f2h(s);
    }
}

// ---------------- correction: o += a @ S_start (128x128 MFMA tiles) ---------
__global__ __launch_bounds__(256) void corr_gemm(
    const __half* __restrict__ Abig, const __half* __restrict__ Cbuf,
    __half* __restrict__ O, int T)
{
    __shared__ __align__(16) _Float16 As[128 * 32];
    __shared__ __align__(16) _Float16 Bs[128 * 32];

    const int tid = threadIdx.x;
    const int p = blockIdx.x;
    const int l = (p & 7) * 112 + (p >> 3);    // 896 blocks, bijective
    const int bhc = l >> 2, mt = (l >> 1) & 1, nt = l & 1;
    const int bh = bhc / 7, ci = bhc - bh * 7;
    const int b = bh >> 2, h = bh & 3;
    const int t0 = (ci + 1) * CL + mt * 128;

    const __half* Ag = Abig + ((size_t)bh * T + t0) * 128;
    const __half* Bg = Cbuf + ((size_t)ci * 32 + bh) * 32768 + (size_t)nt * 128 * 128;
    __half* Og = O + ((size_t)b * T + t0) * 1024 + h * 256 + nt * 128;

    const int wave = tid >> 6, lane = tid & 63;
    const int wm = wave >> 1, wn = wave & 1;
    const int lr = lane & 15, lk = lane >> 4;
    const int srow = tid >> 2;
    const int scol = (tid & 3) * 8;
    char* dA = (char*)As + tid * 16;
    char* dB = (char*)Bs + tid * 16;

    f32x4 acc[4][4] = {};

    for (int k0 = 0; k0 < 128; k0 += 32) {
        const __half* gA0 = Ag + (size_t)srow * 128 + k0 + scol;
        const __half* gA1 = Ag + (size_t)(64 + srow) * 128 + k0 + scol;
        const __half* gB0 = Bg + (size_t)srow * 128 + k0 + scol;
        const __half* gB1 = Bg + (size_t)(64 + srow) * 128 + k0 + scol;
        __syncthreads();
        gload_lds16(gA0, dA);
        gload_lds16(gA1, dA + 4096);
        gload_lds16(gB0, dB);
        gload_lds16(gB1, dB + 4096);
        __syncthreads();

        half8 af[4], bf[4];
#pragma unroll
        for (int f = 0; f < 4; f++) {
            af[f] = *(const half8*)&As[(wm * 64 + f * 16 + lr) * 32 + lk * 8];
            bf[f] = *(const half8*)&Bs[(wn * 64 + f * 16 + lr) * 32 + lk * 8];
        }
#pragma unroll
        for (int fm = 0; fm < 4; fm++)
#pragma unroll
            for (int fn = 0; fn < 4; fn++)
                acc[fm][fn] = __builtin_amdgcn_mfma_f32_16x16x32_f16(
                    af[fm], bf[fn], acc[fm][fn], 0, 0, 0);
    }

#pragma unroll
    for (int fm = 0; fm < 4; fm++) {
#pragma unroll
        for (int fn = 0; fn < 4; fn++) {
#pragma unroll
            for (int j = 0; j < 4; j++) {
                const int row = wm * 64 + fm * 16 + lk * 4 + j;
                const int col = wn * 64 + fn * 16 + lr;
                __half* op = Og + (size_t)row * 1024 + col;
                *op = __float2half(__half2float(*op) + acc[fm][fn][j]);
            }
        }
    }
}

// ---------------- groupnorm + silu gate (f16 in/out) ------------------------
__global__ __launch_bounds__(256) void gn_gate(
    const __half* __restrict__ Obuf, const __half* __restrict__ G,
    const float* __restrict__ gnw, const float* __restrict__ gnb,
    __half* __restrict__ Y)
{
    const int token = blockIdx.x;
    const int wave = threadIdx.x >> 6, lane = threadIdx.x & 63;
    const size_t base = (size_t)token * 1024 + wave * 256 + lane * 4;
    const ushort4 xu = *(const ushort4*)(Obuf + base);
    const float x0 = hbits2f(xu.x), x1 = hbits2f(xu.y),
                x2 = hbits2f(xu.z), x3 = hbits2f(xu.w);
    float sum = x0 + x1 + x2 + x3;
    float ssq = x0 * x0 + x1 * x1 + x2 * x2 + x3 * x3;
#pragma unroll
    for (int off = 32; off >= 1; off >>= 1) {
        sum += __shfl_xor(sum, off);
        ssq += __shfl_xor(ssq, off);
    }
    const float mean = sum * (1.f / 256.f);
    const float var = ssq * (1.f / 256.f) - mean * mean;
    const float rstd = rsqrtf(var + 1e-5f);
    const int c0 = wave * 256 + lane * 4;
    const float4 w4 = *(const float4*)(gnw + c0);
    const float4 b4 = *(const float4*)(gnb + c0);
    const ushort4 gu = *(const ushort4*)(G + base);
    const float g0 = hbits2f(gu.x), g1 = hbits2f(gu.y),
                g2 = hbits2f(gu.z), g3 = hbits2f(gu.w);
    ushort4 y;
    y.x = f2h(((x0 - mean) * rstd * w4.x + b4.x) * (g0 / (1.f + __expf(-g0))));
    y.y = f2h(((x1 - mean) * rstd * w4.y + b4.y) * (g1 / (1.f + __expf(-g1))));
    y.z = f2h(((x2 - mean) * rstd * w4.z + b4.z) * (g2 / (1.f + __expf(-g2))));
    y.w = f2h(((x3 - mean) * rstd * w4.w + b4.w) * (g3 / (1.f + __expf(-g3))));
    *(ushort4*)(Y + base) = y;
}

// ---------------------------------------------------------------------------
extern "C" void kernel_launch(void* const* d_in, const int* in_sizes, int n_in,
                              void* d_out, int out_size, void* d_ws, size_t ws_size,
                              hipStream_t stream)
{
    (void)in_sizes; (void)n_in; (void)out_size; (void)ws_size;
    const float* x      = (const float*)d_in[0];
    const float* mu_x   = (const float*)d_in[1];
    const float* W_x1   = (const float*)d_in[2];
    const float* W_x2   = (const float*)d_in[3];
    const float* x_bias = (const float*)d_in[4];
    const float* W_r    = (const float*)d_in[5];
    const float* W_k    = (const float*)d_in[6];
    const float* W_v    = (const float*)d_in[7];
    const float* W_g    = (const float*)d_in[8];
    const float* A_w    = (const float*)d_in[9];
    const float* B_w    = (const float*)d_in[10];
    const float* b_w    = (const float*)d_in[11];
    const float* bonus  = (const float*)d_in[12];
    const float* gnw    = (const float*)d_in[13];
    const float* gnb    = (const float*)d_in[14];
    const float* W_o    = (const float*)d_in[15];

    const int B = 8, T = 2048, M = B * T;

    // d_out: [xw_h | inb_h] f16 -> [E 48MiB | a 16MiB] -> final f32
    __half* xwh  = (__half*)d_out;
    __half* inbh = xwh + (size_t)M * 1024;
    __half* Abig = (__half*)((char*)d_out + (size_t)48 * 1024 * 1024);

    // ws layout (identical to round-8..17, proven to fit)
    __half* z   = (__half*)d_ws;                    // M*160
    __half* w1  = z   + (size_t)M * 160;            // M*64
    __half* rs  = w1  + (size_t)M * 64;             // M*512
    __half* ks  = rs  + (size_t)M * 512;            // M*512
    __half* wsm = ks  + (size_t)M * 512;            // M*512 (w stream)
    __half* vs  = wsm + (size_t)M * 512;            // M*1024
    __half* gs  = vs  + (size_t)M * 1024;           // M*1024
    float*  ru  = (float*)(gs + (size_t)M * 1024);  // 32*T f32
    __half* wgt = (__half*)(ru + (size_t)32 * T);   // f16 weights (contiguous)
    __half* oh  = rs;                               // overlay: o f16 (r+k dead)
    __half* yb  = wsm;                              // overlay: y f16 (post-corr)
    __half* Cbuf = wsm;                             // overlay: 7*32*32768 f16
    float*  Abuf = (float*)z;                       // overlay: 7*32*128 f32
    __half* xh  = gs;   // x f16: gs region is dead until the n=4 g-GEMM,
                        // which launches after the last xh reader (inb n=4)

    __half* W_x1h = wgt;                 // 160*1024
    __half* W_x2h = W_x1h + 163840;      // 1024*160
    __half* W_rh  = W_x2h + 163840;      // 512*1024
    __half* W_kh  = W_rh + 524288;
    __half* W_vh  = W_kh + 524288;       // 1024*1024
    __half* W_gh  = W_vh + 1048576;
    __half* A_wh  = W_gh + 1048576;      // 64*1024
    __half* B_wh  = A_wh + 65536;        // 512*64
    __half* W_oh  = B_wh + 32768;        // 1024*1024

    const dim3 blk(256);
    // one fused cast for all 9 weight tensors (dst = wgt, contiguous)
    cast_all<<<dim3(4512), blk, 0, stream>>>(W_x1, W_x2, W_r, W_k, W_v, W_g,
                                             A_w, B_w, W_o, wgt);

    // 1. xw = lerp(x, mu_x) -> f16 (d_out) ; xh = f16(x) -> gs region
    k_xw_h<<<(M * 256 + 255) / 256, blk, 0, stream>>>(x, mu_x, xwh, xh, M, T);

    auto ggrid = [&](int N) { return dim3((N + 127) / 128, M / 128); };

    // 2. z = tanh(xw @ W_x1^T)
    gemm16<<<ggrid(160), blk, 0, stream>>>(xwh, 1024, W_x1h, 1024, z, 160,
                                           M, 160, 1024, nullptr, 1, nullptr, T);

    // 3. branches (inb epilogues read xh from gs; g-GEMM overwrites gs last)
    for (int n = 0; n < 5; ++n) {
        gemm16<<<ggrid(1024), blk, 0, stream>>>(z + n * 32, 160, W_x2h + n * 32, 160,
                                                inbh, 1024, M, 1024, 32,
                                                x_bias + n * 1024, 2, xh, T);
        if (n == 1) {
            gemm16<<<ggrid(64), blk, 0, stream>>>(inbh, 1024, A_wh, 1024, w1, 64,
                                                  M, 64, 1024, nullptr, 1, nullptr, T);
            gemm16<<<ggrid(512), blk, 0, stream>>>(w1, 64, B_wh, 64, wsm, 512,
                                                   M, 512, 64, b_w, 3, nullptr, T);
        } else {
            __half* Cp = (n == 0) ? rs : (n == 2) ? ks : (n == 3) ? vs : gs;
            const __half* Wp = (n == 0) ? W_rh : (n == 2) ? W_kh : (n == 3) ? W_vh : W_gh;
            const int N = (n == 0 || n == 2) ? 512 : 1024;
            gemm16<<<ggrid(N), blk, 0, stream>>>(inbh, 1024, Wp, 1024, Cp, N,
                                                 M, N, 1024, nullptr, 0, nullptr, T);
        }
    }

    // 4. prepass -> packed E lines (d_out; xwh/inbh dead), ru
    k_prep<<<dim3(M), blk, 0, stream>>>(rs, ks, wsm, bonus,
                                        (unsigned*)d_out, ru, T);

    // 4b. a_t = r⊙D prefix + Abuf (chunks 1..7)
    a_gen<<<dim3(224), dim3(128), 0, stream>>>((const unsigned*)d_out, Abig,
                                               Abuf, T);

    // 5a. lean scan (8k x 4v, ring-4): local outputs + chunk summaries
    rwkv_scan<<<dim3(1024), blk, 0, stream>>>(
        (const uint4*)d_out, vs, ru, Cbuf, oh, T);
    // 5b. combine -> Cbuf[c-1] = S_start(c)
    rwkv_comb<<<dim3(4096), blk, 0, stream>>>(Cbuf, Abuf);
    // 5c. correction: o += a @ S_start for chunks 1..7
    corr_gemm<<<dim3(896), blk, 0, stream>>>(Abig, Cbuf, oh, T);

    // 6. groupnorm + gate -> yb (Cbuf dead)
    gn_gate<<<dim3(M), blk, 0, stream>>>(oh, gs, gnw, gnb, yb);

    // 7. out = y @ W_o^T -> d_out f32 (E, a dead)
    gemm16<<<ggrid(1024), blk, 0, stream>>>(yb, 1024, W_oh, 1024, d_out, 1024,
                                            M, 1024, 1024, nullptr, 4, nullptr, T);
}